// Round 8
// baseline (34235.754 us; speedup 1.0000x reference)
//
// R8: same numerics contract (fp64 accumulate + fp64 recurrent state) and
// same 5-kernel/step decomposition as R7. Inner-loop fixes:
//  - W staged into LDS as fp64 (cvt once per K-block, was per-use)
//  - bank-conflict-free W tile: pos = c + 2*(c>>4)  (2-way uniform = free)
//  - per kk: 2 ds_read_b64 (A, broadcast) + 2 ds_read_b128 (W) + 8 v_fma_f64
//  - stepA: 52.5 KB LDS -> 3 blocks/CU; small GEMMs: 34 KB -> 4 blocks/CU
// ws_size = 64 MiB (deduced); footprint ~12.6 MB.
#include <hip/hip_runtime.h>
#include <math.h>

#define T_ 128

__device__ __forceinline__ double sigm_d(double x) { return 1.0 / (1.0 + exp(-x)); }

// ---------------------------------------------------------------------------
// Tiled GEMM core: C_tile[32 x COLS] = A[32 rows][0:1024] x W[0:1024][n_off:+COLS]
// A: AT* (double, or float with row stride lda), staged to fp64 LDS [32][65].
// W: fp32 [1024][ldw] original layout, staged to fp64 LDS with pad map
//    pos = c + 2*(c>>4)  (row stride WS), giving uniform 2-way banks (free).
// 256 threads; per-thread 2 rows x CT cols of fp64 accumulators.
// ---------------------------------------------------------------------------
template<int COLS, typename AT, class F>
__device__ __forceinline__ void tile_gemm(double* __restrict__ As,
                                          double* __restrict__ Ws,
                                          const AT* __restrict__ A, long lda,
                                          const float* __restrict__ W, int ldw,
                                          int n_off, F f) {
  constexpr int CT = COLS / 16;                       // 4 or 2 cols/thread
  constexpr int WS = COLS + 2 * ((COLS - CT) >> 4);   // 70 (COLS=64), 34 (32)
  constexpr int RP = 256 / COLS;                      // W rows staged per pass
  const int tid = threadIdx.x;
  const int c0 = (tid & 15) * CT;
  const int wpos = c0 + 2 * (c0 >> 4);
  const int r0 = (tid >> 4) * 2;
  const int abase = r0 * 65;
  const int ar = tid >> 3;                            // A stage row 0..31
  const int ak = (tid & 7) * 8;                       // A stage k base
  const int wn = tid & (COLS - 1);                    // W stage col
  const int wk = tid / COLS;                          // W stage row base
  const int wp = wn + 2 * (wn >> 4);

  double acc[2][CT];
#pragma unroll
  for (int i = 0; i < 2; ++i)
#pragma unroll
    for (int j = 0; j < CT; ++j) acc[i][j] = 0.0;

  for (int k0 = 0; k0 < 1024; k0 += 64) {
    __syncthreads();
    {
      const AT* Ap = A + (size_t)ar * lda + k0 + ak;
#pragma unroll
      for (int i = 0; i < 8; ++i) As[ar * 65 + ak + i] = (double)Ap[i];
    }
    const float* Wp = W + (size_t)(k0 + wk) * ldw + n_off + wn;
#pragma unroll
    for (int p = 0; p < 64 / RP; ++p)
      Ws[(wk + p * RP) * WS + wp] = (double)Wp[(size_t)p * RP * ldw];
    __syncthreads();
#pragma unroll
    for (int kk = 0; kk < 64; ++kk) {
      double a0 = As[abase + kk], a1 = As[abase + 65 + kk];
      const double* wrow = Ws + kk * WS + wpos;
#pragma unroll
      for (int j = 0; j < CT; ++j) {
        double w = wrow[j];
        acc[0][j] = fma(a0, w, acc[0][j]);
        acc[1][j] = fma(a1, w, acc[1][j]);
      }
    }
  }
#pragma unroll
  for (int i = 0; i < 2; ++i)
#pragma unroll
    for (int j = 0; j < CT; ++j) f(r0 + i, c0 + j, acc[i][j]);
}

// ---- init: fp64 master state + tanh copy ----
__global__ __launch_bounds__(256) void k_init(const float* __restrict__ memory,
                                              double* __restrict__ mem,
                                              double* __restrict__ tmem, int n) {
  int i = blockIdx.x * 256 + threadIdx.x;
  if (i >= n) return;
  double v = (double)memory[i];
  mem[i] = v; tmem[i] = tanh(v);
}

// ---- step A (fused): qkvg (480 tiles) + prex (128 tiles) -------------------
__global__ __launch_bounds__(256, 3) void k_stepA(
    const double* __restrict__ mem, const double* __restrict__ tmem,
    const float* __restrict__ inputs,
    const float* __restrict__ Wq, const float* __restrict__ Wk,
    const float* __restrict__ Wv, const float* __restrict__ Ug,
    const float* __restrict__ Wg,
    const float* __restrict__ bq, const float* __restrict__ bk,
    const float* __restrict__ bv, const float* __restrict__ bg,
    const float* __restrict__ bu,
    float* __restrict__ q, float* __restrict__ km, float* __restrict__ vm,
    float* __restrict__ g, float* __restrict__ kx, float* __restrict__ vx,
    float* __restrict__ xg, int t) {
  __shared__ double As[32 * 65];
  __shared__ double Ws[64 * 70];
  int bid = blockIdx.x;
  if (bid < 480) {
    int ct = bid / 6, rt = bid % 6;
    int cb = ct * 64, rb = rt * 32;
    const double* Asrc = ((cb < 3072) ? mem : tmem) + (size_t)rb * 1024;
    const float* W; int ldw, n_off;
    if      (cb < 1024) { W = Wq; ldw = 1024; n_off = cb; }
    else if (cb < 2048) { W = Wk; ldw = 1024; n_off = cb - 1024; }
    else if (cb < 3072) { W = Wv; ldw = 1024; n_off = cb - 2048; }
    else                { W = Ug; ldw = 2048; n_off = cb - 3072; }
    tile_gemm<64>(As, Ws, Asrc, 1024L, W, ldw, n_off,
                  [&](int r, int c, double v) {
      int row = rb + r, col = cb + c;
      if (col < 1024)      q [(size_t)row * 1024 + col]        = (float)(v + (double)bq[col]);
      else if (col < 2048) km[(size_t)row * 1024 + col - 1024] = (float)(v + (double)bk[col - 1024]);
      else if (col < 3072) vm[(size_t)row * 1024 + col - 2048] = (float)(v + (double)bv[col - 2048]);
      else                 g [(size_t)row * 2048 + col - 3072] = (float)v;
    });
  } else {
    int pb = bid - 480;
    int ct = pb / 2, rt = pb % 2;
    int cb = ct * 64, rb = rt * 32;
    const float* Asrc = inputs + (size_t)rb * (T_ * 1024) + (size_t)t * 1024;
    const float* W; int ldw, n_off;
    if      (cb < 1024) { W = Wk; ldw = 1024; n_off = cb; }
    else if (cb < 2048) { W = Wv; ldw = 1024; n_off = cb - 1024; }
    else                { W = Wg; ldw = 2048; n_off = cb - 2048; }
    tile_gemm<64>(As, Ws, Asrc, (long)T_ * 1024, W, ldw, n_off,
                  [&](int r, int c, double v) {
      int b = rb + r, col = cb + c;
      if (col < 1024)      kx[(size_t)b * 1024 + col]        = (float)(v + (double)bk[col]);
      else if (col < 2048) vx[(size_t)b * 1024 + col - 1024] = (float)(v + (double)bv[col - 1024]);
      else { int j = col - 2048; xg[(size_t)b * 2048 + j] = (float)(v + (double)bg[j] + (double)bu[j]); }
    });
  }
}

// ---- step B: tiny attention, one wave per (b,h); fp32 I/O, fp64 math ------
__global__ __launch_bounds__(64) void k_attn(const float* __restrict__ q,
                                             const float* __restrict__ km,
                                             const float* __restrict__ vm,
                                             const float* __restrict__ kx,
                                             const float* __restrict__ vx,
                                             double* __restrict__ o) {
  int bh = blockIdx.x; int b = bh >> 3, h = bh & 7;
  int lane = threadIdx.x;
  int col = h * 128 + lane;                  // lane owns dims (col, col+64)
  double q0[3], q1[3], kk0[4], kk1[4], vv0[4], vv1[4];
#pragma unroll
  for (int s = 0; s < 3; ++s) {
    size_t r = (size_t)(b * 3 + s) * 1024 + col;
    q0[s] = (double)q[r]; q1[s] = (double)q[r + 64];
  }
#pragma unroll
  for (int j = 0; j < 3; ++j) {
    size_t r = (size_t)(b * 3 + j) * 1024 + col;
    kk0[j] = (double)km[r]; kk1[j] = (double)km[r + 64];
    vv0[j] = (double)vm[r]; vv1[j] = (double)vm[r + 64];
  }
  {
    size_t r = (size_t)b * 1024 + col;
    kk0[3] = (double)kx[r]; kk1[3] = (double)kx[r + 64];
    vv0[3] = (double)vx[r]; vv1[3] = (double)vx[r + 64];
  }
  const double scale = 0.08838834764831845;  // 1/sqrt(128)
  double p[3][4];
#pragma unroll
  for (int s = 0; s < 3; ++s)
#pragma unroll
    for (int j = 0; j < 4; ++j) {
      double d = q0[s] * kk0[j] + q1[s] * kk1[j];
#pragma unroll
      for (int off = 32; off > 0; off >>= 1) d += __shfl_xor(d, off);
      p[s][j] = d * scale;
    }
#pragma unroll
  for (int s = 0; s < 3; ++s) {
    double m = fmax(fmax(p[s][0], p[s][1]), fmax(p[s][2], p[s][3]));
    double e0 = exp(p[s][0] - m), e1 = exp(p[s][1] - m);
    double e2 = exp(p[s][2] - m), e3 = exp(p[s][3] - m);
    double inv = 1.0 / (e0 + e1 + e2 + e3);
    double o0 = (e0 * vv0[0] + e1 * vv0[1] + e2 * vv0[2] + e3 * vv0[3]) * inv;
    double o1 = (e0 * vv1[0] + e1 * vv1[1] + e2 * vv1[2] + e3 * vv1[3]) * inv;
    size_t r = (size_t)(b * 3 + s) * 1024 + col;
    o[r] = o0; o[r + 64] = o1;
  }
}

// ---- step C: nm = mem + o@Wo + bo  (M=192, N=1024, 32x32 tiles) ------------
__global__ __launch_bounds__(256, 4) void k_attnout(const double* __restrict__ o,
                                                    const float* __restrict__ Wo,
                                                    const float* __restrict__ bo,
                                                    const double* __restrict__ mem,
                                                    double* __restrict__ nm) {
  __shared__ double As[32 * 65];
  __shared__ double Ws[64 * 34];
  int ct = blockIdx.x / 6, rt = blockIdx.x % 6;
  int cb = ct * 32, rb = rt * 32;
  tile_gemm<32>(As, Ws, o + (size_t)rb * 1024, 1024L, Wo, 1024, cb,
                [&](int r, int c, double v) {
    size_t idx = (size_t)(rb + r) * 1024 + cb + c;
    nm[idx] = mem[idx] + v + (double)bo[cb + c];
  });
}

// ---- step D: h1 = relu(nm@W1 + b1) -----------------------------------------
__global__ __launch_bounds__(256, 4) void k_ff1(const double* __restrict__ nm,
                                                const float* __restrict__ W1,
                                                const float* __restrict__ b1,
                                                double* __restrict__ h1) {
  __shared__ double As[32 * 65];
  __shared__ double Ws[64 * 34];
  int ct = blockIdx.x / 6, rt = blockIdx.x % 6;
  int cb = ct * 32, rb = rt * 32;
  tile_gemm<32>(As, Ws, nm + (size_t)rb * 1024, 1024L, W1, 1024, cb,
                [&](int r, int c, double v) {
    h1[(size_t)(rb + r) * 1024 + cb + c] = fmax(v + (double)b1[cb + c], 0.0);
  });
}

// ---- step E: ml=relu(h1@W2+b2); nm2=nm+ml; gated update; emit out[t] -------
__global__ __launch_bounds__(256, 4) void k_ff2gate(const double* __restrict__ h1,
                                                    const float* __restrict__ W2,
                                                    const float* __restrict__ b2,
                                                    const double* __restrict__ nm,
                                                    const float* __restrict__ xg,
                                                    const float* __restrict__ g,
                                                    double* __restrict__ mem,
                                                    double* __restrict__ tmem,
                                                    float* __restrict__ out, int t) {
  __shared__ double As[32 * 65];
  __shared__ double Ws[64 * 34];
  int ct = blockIdx.x / 6, rt = blockIdx.x % 6;
  int cb = ct * 32, rb = rt * 32;
  tile_gemm<32>(As, Ws, h1 + (size_t)rb * 1024, 1024L, W2, 1024, cb,
                [&](int r, int c, double v) {
    int row = rb + r, col = cb + c;
    size_t idx = (size_t)row * 1024 + col;
    double ml = fmax(v + (double)b2[col], 0.0);
    double nm2 = nm[idx] + ml;
    int b = row / 3;
    int s = row - b * 3;
    double ig = (double)xg[(size_t)b * 2048 + col]        + (double)g[(size_t)row * 2048 + col];
    double fg = (double)xg[(size_t)b * 2048 + 1024 + col] + (double)g[(size_t)row * 2048 + 1024 + col];
    double old = mem[idx];
    double nv = sigm_d(ig) * tanh(nm2) + sigm_d(fg) * old;
    out[(size_t)(b * T_ + t) * 3072 + s * 1024 + col] = (float)nv;
    mem[idx]  = nv;
    tmem[idx] = tanh(nv);
  });
}

// ---------------------------------------------------------------------------
extern "C" void kernel_launch(void* const* d_in, const int* in_sizes, int n_in,
                              void* d_out, int out_size, void* d_ws, size_t ws_size,
                              hipStream_t stream) {
  (void)in_sizes; (void)n_in; (void)out_size;
  const float* inputs = (const float*)d_in[0];
  const float* memory = (const float*)d_in[1];
  const float* Wq = (const float*)d_in[2];  const float* bq = (const float*)d_in[3];
  const float* Wk = (const float*)d_in[4];  const float* bk = (const float*)d_in[5];
  const float* Wv = (const float*)d_in[6];  const float* bv = (const float*)d_in[7];
  const float* Wo = (const float*)d_in[8];  const float* bo = (const float*)d_in[9];
  const float* W1 = (const float*)d_in[10]; const float* b1 = (const float*)d_in[11];
  const float* W2 = (const float*)d_in[12]; const float* b2 = (const float*)d_in[13];
  const float* Wg = (const float*)d_in[14]; const float* bg = (const float*)d_in[15];
  const float* Ug = (const float*)d_in[16]; const float* bu = (const float*)d_in[17];
  float* out = (float*)d_out;

  // Footprint ~12.6 MB (ws = 64 MiB). Bail-signature if wrong: absmax 4.3125.
  if (ws_size < (size_t)16 * 1024 * 1024) return;

  char* ws = (char*)d_ws;
  size_t off = 0;
  auto alloc = [&](size_t bytes) -> void* {
    void* p = ws + off; off += (bytes + 255) & ~(size_t)255; return p;
  };
  double* mem  = (double*)alloc((size_t)196608 * 8);
  double* tmem = (double*)alloc((size_t)196608 * 8);
  double* nm   = (double*)alloc((size_t)196608 * 8);
  double* o    = (double*)alloc((size_t)196608 * 8);
  double* h1   = (double*)alloc((size_t)196608 * 8);
  float* q  = (float*)alloc((size_t)196608 * 4);
  float* km = (float*)alloc((size_t)196608 * 4);
  float* vm = (float*)alloc((size_t)196608 * 4);
  float* g  = (float*)alloc((size_t)192 * 2048 * 4);
  float* kx = (float*)alloc((size_t)64 * 1024 * 4);
  float* vx = (float*)alloc((size_t)64 * 1024 * 4);
  float* xg = (float*)alloc((size_t)64 * 2048 * 4);

  k_init<<<768, 256, 0, stream>>>(memory, mem, tmem, 196608);

  for (int t = 0; t < T_; ++t) {
    k_stepA<<<608, 256, 0, stream>>>(mem, tmem, inputs, Wq, Wk, Wv, Ug, Wg,
                                     bq, bk, bv, bg, bu,
                                     q, km, vm, g, kx, vx, xg, t);
    k_attn<<<512, 64, 0, stream>>>(q, km, vm, kx, vx, o);
    k_attnout<<<192, 256, 0, stream>>>(o, Wo, bo, mem, nm);
    k_ff1<<<192, 256, 0, stream>>>(nm, W1, b1, h1);
    k_ff2gate<<<192, 256, 0, stream>>>(h1, W2, b2, nm, xg, g, mem, tmem, out, t);
  }
}

// Round 9
// 28496.902 us; speedup vs baseline: 1.2014x; 1.2014x over previous
//
// R9: latency-focused round. Same 5-kernel/step decomposition and numerics
// contract (fp64 accumulate + fp64 recurrent state) as R7/R8. Changes:
//  - reg-prefetch staging: ds_write -> barrier -> issue next loads -> compute
//    -> barrier. Global latency hides under the 64-kk compute phase (HIP's
//    vmcnt(0)-before-barrier drain is then satisfied for free).
//  - W staged fp32 in LDS (cvt at use -- proven free by R7==R8), halving LDS:
//    stepA = 34KB -> 4 blocks/CU (__launch_bounds__(256,4)).
#include <hip/hip_runtime.h>
#include <math.h>

#define T_ 128

__device__ __forceinline__ double sigm_d(double x) { return 1.0 / (1.0 + exp(-x)); }

// ---------------------------------------------------------------------------
// Prefetched tiled GEMM: C_tile[32 x COLS] = A[32 rows][0:1024] x W[.][n_off:+COLS]
// A: AT* (double / float, row stride lda) -> fp64 LDS As[32][65].
// W: fp32 [1024][ldw] original layout -> fp32 LDS Ws[64][COLS+4], cvt at use.
// 256 threads; per-thread 2 rows x CT cols fp64 acc.
// Chunk loop: write LDS from regs; barrier; issue chunk+1 loads; compute;
// barrier. Prefetch latency hides under compute (~2000cyc > ~900cyc).
// ---------------------------------------------------------------------------
template<int COLS, typename AT, class F>
__device__ __forceinline__ void tile_gemm_pf(double* __restrict__ As,
                                             float* __restrict__ Ws,
                                             const AT* __restrict__ A, long lda,
                                             const float* __restrict__ W, int ldw,
                                             int n_off, F f) {
  constexpr int CT = COLS / 16;            // cols per thread (4 or 2)
  constexpr int WP = COLS + 4;             // padded W row stride (floats)
  constexpr int RP = 256 / COLS;           // W rows staged per pass
  constexpr int WL = 64 / RP;              // W loads per thread per chunk
  const int tid = threadIdx.x;
  const int c0 = (tid & 15) * CT;
  const int r0 = (tid >> 4) * 2;
  const int ar = tid >> 3;                 // A stage row 0..31
  const int ak = (tid & 7) * 8;            // A stage k base
  const int wn = tid & (COLS - 1);         // W stage col
  const int wk = tid / COLS;               // W stage row base

  double aReg[8];
  float  wReg[WL];
  // prologue: load chunk 0
  {
    const AT* Ap = A + (size_t)ar * lda + ak;
#pragma unroll
    for (int i = 0; i < 8; ++i) aReg[i] = (double)Ap[i];
    const float* Wp = W + (size_t)wk * ldw + n_off + wn;
#pragma unroll
    for (int p = 0; p < WL; ++p) wReg[p] = Wp[(size_t)p * RP * ldw];
  }
  double acc[2][CT];
#pragma unroll
  for (int i = 0; i < 2; ++i)
#pragma unroll
    for (int j = 0; j < CT; ++j) acc[i][j] = 0.0;

  for (int k0 = 0; k0 < 1024; k0 += 64) {
    // write staged regs to LDS (vmcnt dependency already satisfied)
#pragma unroll
    for (int i = 0; i < 8; ++i) As[ar * 65 + ak + i] = aReg[i];
#pragma unroll
    for (int p = 0; p < WL; ++p) Ws[(wk + p * RP) * WP + wn] = wReg[p];
    __syncthreads();                       // cheap: nothing in flight
    if (k0 + 64 < 1024) {                  // issue next chunk's loads now;
      const AT* Ap = A + (size_t)ar * lda + (k0 + 64) + ak;
#pragma unroll
      for (int i = 0; i < 8; ++i) aReg[i] = (double)Ap[i];
      const float* Wp = W + (size_t)(k0 + 64 + wk) * ldw + n_off + wn;
#pragma unroll
      for (int p = 0; p < WL; ++p) wReg[p] = Wp[(size_t)p * RP * ldw];
    }
    // compute chunk (latency of the above loads hides under this)
#pragma unroll
    for (int kk = 0; kk < 64; ++kk) {
      double a0 = As[r0 * 65 + kk], a1 = As[(r0 + 1) * 65 + kk];
      const float* wrow = Ws + kk * WP + c0;
#pragma unroll
      for (int j = 0; j < CT; ++j) {
        double w = (double)wrow[j];
        acc[0][j] = fma(a0, w, acc[0][j]);
        acc[1][j] = fma(a1, w, acc[1][j]);
      }
    }
    __syncthreads();                       // drain: loads landed during compute
  }
#pragma unroll
  for (int i = 0; i < 2; ++i)
#pragma unroll
    for (int j = 0; j < CT; ++j) f(r0 + i, c0 + j, acc[i][j]);
}

// ---- init: fp64 master state + tanh copy ----
__global__ __launch_bounds__(256) void k_init(const float* __restrict__ memory,
                                              double* __restrict__ mem,
                                              double* __restrict__ tmem, int n) {
  int i = blockIdx.x * 256 + threadIdx.x;
  if (i >= n) return;
  double v = (double)memory[i];
  mem[i] = v; tmem[i] = tanh(v);
}

// ---- step A (fused): qkvg (480 tiles) + prex (128 tiles) -------------------
__global__ __launch_bounds__(256, 4) void k_stepA(
    const double* __restrict__ mem, const double* __restrict__ tmem,
    const float* __restrict__ inputs,
    const float* __restrict__ Wq, const float* __restrict__ Wk,
    const float* __restrict__ Wv, const float* __restrict__ Ug,
    const float* __restrict__ Wg,
    const float* __restrict__ bq, const float* __restrict__ bk,
    const float* __restrict__ bv, const float* __restrict__ bg,
    const float* __restrict__ bu,
    float* __restrict__ q, float* __restrict__ km, float* __restrict__ vm,
    float* __restrict__ g, float* __restrict__ kx, float* __restrict__ vx,
    float* __restrict__ xg, int t) {
  __shared__ double As[32 * 65];
  __shared__ float  Ws[64 * 68];
  int bid = blockIdx.x;
  if (bid < 480) {
    int ct = bid / 6, rt = bid % 6;
    int cb = ct * 64, rb = rt * 32;
    const double* Asrc = ((cb < 3072) ? mem : tmem) + (size_t)rb * 1024;
    const float* W; int ldw, n_off;
    if      (cb < 1024) { W = Wq; ldw = 1024; n_off = cb; }
    else if (cb < 2048) { W = Wk; ldw = 1024; n_off = cb - 1024; }
    else if (cb < 3072) { W = Wv; ldw = 1024; n_off = cb - 2048; }
    else                { W = Ug; ldw = 2048; n_off = cb - 3072; }
    tile_gemm_pf<64>(As, Ws, Asrc, 1024L, W, ldw, n_off,
                     [&](int r, int c, double v) {
      int row = rb + r, col = cb + c;
      if (col < 1024)      q [(size_t)row * 1024 + col]        = (float)(v + (double)bq[col]);
      else if (col < 2048) km[(size_t)row * 1024 + col - 1024] = (float)(v + (double)bk[col - 1024]);
      else if (col < 3072) vm[(size_t)row * 1024 + col - 2048] = (float)(v + (double)bv[col - 2048]);
      else                 g [(size_t)row * 2048 + col - 3072] = (float)v;
    });
  } else {
    int pb = bid - 480;
    int ct = pb / 2, rt = pb % 2;
    int cb = ct * 64, rb = rt * 32;
    const float* Asrc = inputs + (size_t)rb * (T_ * 1024) + (size_t)t * 1024;
    const float* W; int ldw, n_off;
    if      (cb < 1024) { W = Wk; ldw = 1024; n_off = cb; }
    else if (cb < 2048) { W = Wv; ldw = 1024; n_off = cb - 1024; }
    else                { W = Wg; ldw = 2048; n_off = cb - 2048; }
    tile_gemm_pf<64>(As, Ws, Asrc, (long)T_ * 1024, W, ldw, n_off,
                     [&](int r, int c, double v) {
      int b = rb + r, col = cb + c;
      if (col < 1024)      kx[(size_t)b * 1024 + col]        = (float)(v + (double)bk[col]);
      else if (col < 2048) vx[(size_t)b * 1024 + col - 1024] = (float)(v + (double)bv[col - 1024]);
      else { int j = col - 2048; xg[(size_t)b * 2048 + j] = (float)(v + (double)bg[j] + (double)bu[j]); }
    });
  }
}

// ---- step B: tiny attention, one wave per (b,h); fp32 I/O, fp64 math ------
__global__ __launch_bounds__(64) void k_attn(const float* __restrict__ q,
                                             const float* __restrict__ km,
                                             const float* __restrict__ vm,
                                             const float* __restrict__ kx,
                                             const float* __restrict__ vx,
                                             double* __restrict__ o) {
  int bh = blockIdx.x; int b = bh >> 3, h = bh & 7;
  int lane = threadIdx.x;
  int col = h * 128 + lane;                  // lane owns dims (col, col+64)
  double q0[3], q1[3], kk0[4], kk1[4], vv0[4], vv1[4];
#pragma unroll
  for (int s = 0; s < 3; ++s) {
    size_t r = (size_t)(b * 3 + s) * 1024 + col;
    q0[s] = (double)q[r]; q1[s] = (double)q[r + 64];
  }
#pragma unroll
  for (int j = 0; j < 3; ++j) {
    size_t r = (size_t)(b * 3 + j) * 1024 + col;
    kk0[j] = (double)km[r]; kk1[j] = (double)km[r + 64];
    vv0[j] = (double)vm[r]; vv1[j] = (double)vm[r + 64];
  }
  {
    size_t r = (size_t)b * 1024 + col;
    kk0[3] = (double)kx[r]; kk1[3] = (double)kx[r + 64];
    vv0[3] = (double)vx[r]; vv1[3] = (double)vx[r + 64];
  }
  const double scale = 0.08838834764831845;  // 1/sqrt(128)
  double p[3][4];
#pragma unroll
  for (int s = 0; s < 3; ++s)
#pragma unroll
    for (int j = 0; j < 4; ++j) {
      double d = q0[s] * kk0[j] + q1[s] * kk1[j];
#pragma unroll
      for (int off = 32; off > 0; off >>= 1) d += __shfl_xor(d, off);
      p[s][j] = d * scale;
    }
#pragma unroll
  for (int s = 0; s < 3; ++s) {
    double m = fmax(fmax(p[s][0], p[s][1]), fmax(p[s][2], p[s][3]));
    double e0 = exp(p[s][0] - m), e1 = exp(p[s][1] - m);
    double e2 = exp(p[s][2] - m), e3 = exp(p[s][3] - m);
    double inv = 1.0 / (e0 + e1 + e2 + e3);
    double o0 = (e0 * vv0[0] + e1 * vv0[1] + e2 * vv0[2] + e3 * vv0[3]) * inv;
    double o1 = (e0 * vv1[0] + e1 * vv1[1] + e2 * vv1[2] + e3 * vv1[3]) * inv;
    size_t r = (size_t)(b * 3 + s) * 1024 + col;
    o[r] = o0; o[r + 64] = o1;
  }
}

// ---- step C: nm = mem + o@Wo + bo  (M=192, N=1024, 32x32 tiles) ------------
__global__ __launch_bounds__(256) void k_attnout(const double* __restrict__ o,
                                                 const float* __restrict__ Wo,
                                                 const float* __restrict__ bo,
                                                 const double* __restrict__ mem,
                                                 double* __restrict__ nm) {
  __shared__ double As[32 * 65];
  __shared__ float  Ws[64 * 36];
  int ct = blockIdx.x / 6, rt = blockIdx.x % 6;
  int cb = ct * 32, rb = rt * 32;
  tile_gemm_pf<32>(As, Ws, o + (size_t)rb * 1024, 1024L, Wo, 1024, cb,
                   [&](int r, int c, double v) {
    size_t idx = (size_t)(rb + r) * 1024 + cb + c;
    nm[idx] = mem[idx] + v + (double)bo[cb + c];
  });
}

// ---- step D: h1 = relu(nm@W1 + b1) -----------------------------------------
__global__ __launch_bounds__(256) void k_ff1(const double* __restrict__ nm,
                                             const float* __restrict__ W1,
                                             const float* __restrict__ b1,
                                             double* __restrict__ h1) {
  __shared__ double As[32 * 65];
  __shared__ float  Ws[64 * 36];
  int ct = blockIdx.x / 6, rt = blockIdx.x % 6;
  int cb = ct * 32, rb = rt * 32;
  tile_gemm_pf<32>(As, Ws, nm + (size_t)rb * 1024, 1024L, W1, 1024, cb,
                   [&](int r, int c, double v) {
    h1[(size_t)(rb + r) * 1024 + cb + c] = fmax(v + (double)b1[cb + c], 0.0);
  });
}

// ---- step E: ml=relu(h1@W2+b2); nm2=nm+ml; gated update; emit out[t] -------
__global__ __launch_bounds__(256) void k_ff2gate(const double* __restrict__ h1,
                                                 const float* __restrict__ W2,
                                                 const float* __restrict__ b2,
                                                 const double* __restrict__ nm,
                                                 const float* __restrict__ xg,
                                                 const float* __restrict__ g,
                                                 double* __restrict__ mem,
                                                 double* __restrict__ tmem,
                                                 float* __restrict__ out, int t) {
  __shared__ double As[32 * 65];
  __shared__ float  Ws[64 * 36];
  int ct = blockIdx.x / 6, rt = blockIdx.x % 6;
  int cb = ct * 32, rb = rt * 32;
  tile_gemm_pf<32>(As, Ws, h1 + (size_t)rb * 1024, 1024L, W2, 1024, cb,
                   [&](int r, int c, double v) {
    int row = rb + r, col = cb + c;
    size_t idx = (size_t)row * 1024 + col;
    double ml = fmax(v + (double)b2[col], 0.0);
    double nm2 = nm[idx] + ml;
    int b = row / 3;
    int s = row - b * 3;
    double ig = (double)xg[(size_t)b * 2048 + col]        + (double)g[(size_t)row * 2048 + col];
    double fg = (double)xg[(size_t)b * 2048 + 1024 + col] + (double)g[(size_t)row * 2048 + 1024 + col];
    double old = mem[idx];
    double nv = sigm_d(ig) * tanh(nm2) + sigm_d(fg) * old;
    out[(size_t)(b * T_ + t) * 3072 + s * 1024 + col] = (float)nv;
    mem[idx]  = nv;
    tmem[idx] = tanh(nv);
  });
}

// ---------------------------------------------------------------------------
extern "C" void kernel_launch(void* const* d_in, const int* in_sizes, int n_in,
                              void* d_out, int out_size, void* d_ws, size_t ws_size,
                              hipStream_t stream) {
  (void)in_sizes; (void)n_in; (void)out_size;
  const float* inputs = (const float*)d_in[0];
  const float* memory = (const float*)d_in[1];
  const float* Wq = (const float*)d_in[2];  const float* bq = (const float*)d_in[3];
  const float* Wk = (const float*)d_in[4];  const float* bk = (const float*)d_in[5];
  const float* Wv = (const float*)d_in[6];  const float* bv = (const float*)d_in[7];
  const float* Wo = (const float*)d_in[8];  const float* bo = (const float*)d_in[9];
  const float* W1 = (const float*)d_in[10]; const float* b1 = (const float*)d_in[11];
  const float* W2 = (const float*)d_in[12]; const float* b2 = (const float*)d_in[13];
  const float* Wg = (const float*)d_in[14]; const float* bg = (const float*)d_in[15];
  const float* Ug = (const float*)d_in[16]; const float* bu = (const float*)d_in[17];
  float* out = (float*)d_out;

  // Footprint ~12.6 MB (ws = 64 MiB). Bail-signature if wrong: absmax 4.3125.
  if (ws_size < (size_t)16 * 1024 * 1024) return;

  char* ws = (char*)d_ws;
  size_t off = 0;
  auto alloc = [&](size_t bytes) -> void* {
    void* p = ws + off; off += (bytes + 255) & ~(size_t)255; return p;
  };
  double* mem  = (double*)alloc((size_t)196608 * 8);
  double* tmem = (double*)alloc((size_t)196608 * 8);
  double* nm   = (double*)alloc((size_t)196608 * 8);
  double* o    = (double*)alloc((size_t)196608 * 8);
  double* h1   = (double*)alloc((size_t)196608 * 8);
  float* q  = (float*)alloc((size_t)196608 * 4);
  float* km = (float*)alloc((size_t)196608 * 4);
  float* vm = (float*)alloc((size_t)196608 * 4);
  float* g  = (float*)alloc((size_t)192 * 2048 * 4);
  float* kx = (float*)alloc((size_t)64 * 1024 * 4);
  float* vx = (float*)alloc((size_t)64 * 1024 * 4);
  float* xg = (float*)alloc((size_t)64 * 2048 * 4);

  k_init<<<768, 256, 0, stream>>>(memory, mem, tmem, 196608);

  for (int t = 0; t < T_; ++t) {
    k_stepA<<<608, 256, 0, stream>>>(mem, tmem, inputs, Wq, Wk, Wv, Ug, Wg,
                                     bq, bk, bv, bg, bu,
                                     q, km, vm, g, kx, vx, xg, t);
    k_attn<<<512, 64, 0, stream>>>(q, km, vm, kx, vx, o);
    k_attnout<<<192, 256, 0, stream>>>(o, Wo, bo, mem, nm);
    k_ff1<<<192, 256, 0, stream>>>(nm, W1, b1, h1);
    k_ff2gate<<<192, 256, 0, stream>>>(h1, W2, b2, nm, xg, g, mem, tmem, out, t);
  }
}